// Round 3
// baseline (630.992 us; speedup 1.0000x reference)
//
#include <hip/hip_runtime.h>
#include <hip/hip_bf16.h>

typedef unsigned short ushort_t;
typedef short short8 __attribute__((ext_vector_type(8)));
typedef float f32x4 __attribute__((ext_vector_type(4)));

typedef unsigned int u32;
typedef u32 __attribute__((address_space(1))) global_u32;
typedef u32 __attribute__((address_space(3))) lds_u32;

#define D_ 1024
#define L_ 2048
#define B_ 2
#define H_ 16
#define DH_ 64
#define FF_ 2048
#define ADA_ 6144

__device__ __forceinline__ ushort_t f2bf(float f) {
    union { float f; u32 u; } v; v.f = f;
    u32 r = v.u + 0x7fffu + ((v.u >> 16) & 1u);
    return (ushort_t)(r >> 16);
}

__device__ __forceinline__ void llds16(const ushort_t* src, ushort_t* dst) {
    __builtin_amdgcn_global_load_lds((global_u32*)src, (lds_u32*)dst, 16, 0, 0);
}

// ---------------- weight transpose+convert: W (K,N) fp32 -> Wt (N,K) bf16 ----
__global__ void transpose_w(const float* __restrict__ W, ushort_t* __restrict__ Wt,
                            int K, int N) {
    __shared__ float tile[64][65];
    int n0 = blockIdx.x * 64, k0 = blockIdx.y * 64;
    int t = threadIdx.x;
    for (int p = 0; p < 4; ++p) {
        int k = p * 16 + (t >> 4), nn = (t & 15) * 4;
        float4 v = *(const float4*)(W + (size_t)(k0 + k) * N + n0 + nn);
        tile[k][nn] = v.x; tile[k][nn + 1] = v.y; tile[k][nn + 2] = v.z; tile[k][nn + 3] = v.w;
    }
    __syncthreads();
    for (int p = 0; p < 4; ++p) {
        int n = p * 16 + (t >> 4), kk = (t & 15) * 4;
        ushort4 o;
        o.x = f2bf(tile[kk][n]); o.y = f2bf(tile[kk + 1][n]);
        o.z = f2bf(tile[kk + 2][n]); o.w = f2bf(tile[kk + 3][n]);
        *(ushort4*)(Wt + (size_t)(n0 + n) * K + k0 + kk) = o;
    }
}

// ---------------- V transpose: (BH, L, DH) bf16 -> (BH, DH, L) bf16 ----------
__global__ void transpose_v(const ushort_t* __restrict__ V, ushort_t* __restrict__ Vt) {
    __shared__ ushort_t tile[64][72];
    int bh = blockIdx.y, l0 = blockIdx.x * 64;
    const ushort_t* Vb = V + ((size_t)bh * L_ + l0) * DH_;
    ushort_t* Vtb = Vt + (size_t)bh * DH_ * L_;
    int t = threadIdx.x;
    for (int p = 0; p < 2; ++p) {
        int i = p * 32 + (t >> 3), d0 = (t & 7) * 8;
        short8 v = *(const short8*)(Vb + (size_t)i * DH_ + d0);
        for (int j = 0; j < 8; ++j) tile[d0 + j][i] = (ushort_t)v[j];
    }
    __syncthreads();
    for (int p = 0; p < 2; ++p) {
        int dh = p * 32 + (t >> 3), j0 = (t & 7) * 8;
        short8 o;
        for (int j = 0; j < 8; ++j) o[j] = (short)tile[dh][j0 + j];
        *(short8*)(Vtb + (size_t)dh * L_ + l0 + j0) = o;
    }
}

// ---------------- ada = silu(c) @ Wada + bada  (fp32 GEMV, B=2) --------------
__global__ void ada_gemv(const float* __restrict__ c, const float* __restrict__ Wada,
                         const float* __restrict__ bada, float* __restrict__ ada) {
    int b = blockIdx.y;
    int j = blockIdx.x * 256 + threadIdx.x;
    __shared__ float s[D_];
    for (int d = threadIdx.x; d < D_; d += 256) {
        float v = c[(size_t)b * D_ + d];
        s[d] = v / (1.f + __expf(-v));
    }
    __syncthreads();
    float acc = 0.f;
#pragma unroll 8
    for (int d = 0; d < D_; ++d)
        acc = fmaf(s[d], Wada[(size_t)d * ADA_ + j], acc);
    ada[(size_t)b * ADA_ + j] = acc + bada[j];
}

// ---------------- LayerNorm + modulation -> bf16 -----------------------------
__global__ void ln_mod(const float* __restrict__ x, const float* __restrict__ ada,
                       int so, int co, ushort_t* __restrict__ out) {
    int row = blockIdx.x;
    int b = row >> 11;
    float4 v = ((const float4*)(x + (size_t)row * D_))[threadIdx.x];
    float sum = v.x + v.y + v.z + v.w;
    float sq = v.x * v.x + v.y * v.y + v.z * v.z + v.w * v.w;
    for (int off = 32; off; off >>= 1) { sum += __shfl_down(sum, off); sq += __shfl_down(sq, off); }
    __shared__ float sa[4], sb[4];
    int wave = threadIdx.x >> 6, lane = threadIdx.x & 63;
    if (lane == 0) { sa[wave] = sum; sb[wave] = sq; }
    __syncthreads();
    sum = sa[0] + sa[1] + sa[2] + sa[3];
    sq = sb[0] + sb[1] + sb[2] + sb[3];
    float mean = sum * (1.f / 1024.f);
    float var = sq * (1.f / 1024.f) - mean * mean;
    float rstd = rsqrtf(var + 1e-6f);
    int d = threadIdx.x * 4;
    const float* shf = ada + (size_t)b * ADA_ + so;
    const float* scf = ada + (size_t)b * ADA_ + co;
    ushort4 ov;
    ov.x = f2bf((v.x - mean) * rstd * (1.f + scf[d + 0]) + shf[d + 0]);
    ov.y = f2bf((v.y - mean) * rstd * (1.f + scf[d + 1]) + shf[d + 1]);
    ov.z = f2bf((v.z - mean) * rstd * (1.f + scf[d + 2]) + shf[d + 2]);
    ov.w = f2bf((v.w - mean) * rstd * (1.f + scf[d + 3]) + shf[d + 3]);
    *(ushort4*)(out + (size_t)row * D_ + d) = ov;
}

// ---------------- GEMM: A (M,K) bf16 row-major, Bt (N,K) bf16 row-major ------
// 128x128 tile, BK=64, 4 waves of 64x64, mfma 16x16x32 bf16.
// XOR-swizzled global_load_lds staging: LDS slot (row, g') holds data group
// g = g' ^ (row&7), so fragment ds_read_b128 is 2-way-conflict-free.
struct EpiArgs {
    const float* bias0; const float* bias1; const float* bias2;
    ushort_t* o0; ushort_t* o1; ushort_t* o2;
    const float* resid; const float* gate;
    float* fout;
};

template <int EPI>
__global__ __launch_bounds__(256, 2) void gemm_bt(
    const ushort_t* __restrict__ A, const ushort_t* __restrict__ Bt,
    int M, int N, int K, EpiArgs e) {
    __shared__ ushort_t As[128 * 64];
    __shared__ ushort_t Bs[128 * 64];
    int m0 = blockIdx.x * 128, n0 = blockIdx.y * 128;
    int tid = threadIdx.x, wave = tid >> 6, lane = tid & 63;
    int quad = lane >> 4, lc = lane & 15;
    int wm = (wave & 1) * 64, wn = (wave >> 1) * 64;

    f32x4 acc[4][4] = {};
    int srow = lane >> 3, sg = lane & 7;

    for (int k0 = 0; k0 < K; k0 += 64) {
        for (int i = 0; i < 8; ++i) {
            int chunk = wave * 8 + i;
            int c = chunk & 15;
            int row = c * 8 + srow;
            int g = sg ^ (row & 7);
            if (chunk < 16)
                llds16(A + (size_t)(m0 + row) * K + k0 + g * 8, &As[c * 512 + lane * 8]);
            else
                llds16(Bt + (size_t)(n0 + row) * K + k0 + g * 8, &Bs[c * 512 + lane * 8]);
        }
        __syncthreads();
        for (int kk = 0; kk < 2; ++kk) {
            int gq = kk * 4 + quad;
            short8 a[4], b[4];
            for (int mi = 0; mi < 4; ++mi) {
                int r = wm + mi * 16 + lc;
                a[mi] = *(const short8*)&As[r * 64 + ((gq ^ (r & 7)) * 8)];
            }
            for (int ni = 0; ni < 4; ++ni) {
                int r = wn + ni * 16 + lc;
                b[ni] = *(const short8*)&Bs[r * 64 + ((gq ^ (r & 7)) * 8)];
            }
            for (int mi = 0; mi < 4; ++mi)
                for (int ni = 0; ni < 4; ++ni)
                    acc[mi][ni] = __builtin_amdgcn_mfma_f32_16x16x32_bf16(a[mi], b[ni], acc[mi][ni], 0, 0, 0);
        }
        __syncthreads();
    }

    for (int mi = 0; mi < 4; ++mi)
        for (int ni = 0; ni < 4; ++ni)
            for (int r = 0; r < 4; ++r) {
                int m = m0 + wm + mi * 16 + quad * 4 + r;
                int n = n0 + wn + ni * 16 + lc;
                float v = acc[mi][ni][r];
                if (EPI == 0) {  // QKV epilogue -> (B,H,L,DH) bf16, Q pre-scaled
                    int which = n >> 10, cc = n & 1023;
                    const float* bias = which == 0 ? e.bias0 : which == 1 ? e.bias1 : e.bias2;
                    ushort_t* ob = which == 0 ? e.o0 : which == 1 ? e.o1 : e.o2;
                    v += bias[cc];
                    if (which == 0) v *= 0.125f;  // 1/sqrt(DH)
                    int b = m >> 11, l = m & 2047, h = cc >> 6, dh = cc & 63;
                    ob[(((size_t)(b * H_ + h) * L_) + l) * DH_ + dh] = f2bf(v);
                } else if (EPI == 1) {  // bias + exact GELU -> bf16
                    v += e.bias0[n];
                    v = 0.5f * v * (1.f + erff(v * 0.70710678118f));
                    e.o0[(size_t)m * N + n] = f2bf(v);
                } else {  // residual + gate -> fp32
                    int b = m >> 11;
                    float out = e.resid[(size_t)m * N + n] + e.gate[(size_t)b * ADA_ + n] * (v + e.bias0[n]);
                    e.fout[(size_t)m * N + n] = out;
                }
            }
}

// ---------------- flash attention: Q pre-scaled, per (b,h,qtile) -------------
__global__ __launch_bounds__(256, 2) void attn(
    const ushort_t* __restrict__ Q, const ushort_t* __restrict__ Kx,
    const ushort_t* __restrict__ Vt, ushort_t* __restrict__ O) {
    __shared__ ushort_t Qs[128 * 64], Ks[128 * 64], Vs[64 * 128], Ps[4 * 32 * 128];
    int qt = blockIdx.x, bh = blockIdx.y;
    const ushort_t* Qg = Q + ((size_t)bh * L_ + qt * 128) * DH_;
    const ushort_t* Kg = Kx + (size_t)bh * L_ * DH_;
    const ushort_t* Vg = Vt + (size_t)bh * DH_ * L_;
    int tid = threadIdx.x, wave = tid >> 6, lane = tid & 63;
    int quad = lane >> 4, lc = lane & 15;

    {   // stage Q (wave w stages exactly the rows it will consume)
        int srow = lane >> 3, sg = lane & 7;
        for (int i = 0; i < 4; ++i) {
            int c = wave * 4 + i;
            int row = c * 8 + srow;
            int g = sg ^ (row & 7);
            llds16(Qg + (size_t)row * DH_ + g * 8, &Qs[c * 512 + lane * 8]);
        }
    }

    f32x4 o[2][4] = {};
    float mrow[2][4], lrow[2][4];
    for (int pi = 0; pi < 2; ++pi)
        for (int r = 0; r < 4; ++r) { mrow[pi][r] = -1e30f; lrow[pi][r] = 0.f; }
    ushort_t* Pw = &Ps[wave * 4096];

    for (int t = 0; t < 16; ++t) {
        {   // stage K tile (chunks 0..15) and Vt tile (chunks 16..31)
            int srow = lane >> 3, sg = lane & 7;
            for (int i = 0; i < 8; ++i) {
                int chunk = wave * 8 + i;
                if (chunk < 16) {
                    int row = chunk * 8 + srow;
                    int g = sg ^ (row & 7);
                    llds16(Kg + ((size_t)(t * 128 + row)) * DH_ + g * 8, &Ks[chunk * 512 + lane * 8]);
                } else {
                    int c2 = chunk - 16;
                    int row = c2 * 4 + (lane >> 4);
                    int g = (lane & 15) ^ (row & 15);
                    llds16(Vg + (size_t)row * L_ + t * 128 + g * 8, &Vs[c2 * 512 + lane * 8]);
                }
            }
        }
        __syncthreads();

        // S = Q K^T for this wave's 32 q-rows
        short8 aq[2][2];
        for (int pi = 0; pi < 2; ++pi)
            for (int kk = 0; kk < 2; ++kk) {
                int r = wave * 32 + pi * 16 + lc;
                int gq = kk * 4 + quad;
                aq[pi][kk] = *(const short8*)&Qs[r * 64 + ((gq ^ (r & 7)) * 8)];
            }
        f32x4 s[2][8];
        for (int ni = 0; ni < 8; ++ni) {
            int r = ni * 16 + lc;
            short8 b0 = *(const short8*)&Ks[r * 64 + (((0 + quad) ^ (r & 7)) * 8)];
            short8 b1 = *(const short8*)&Ks[r * 64 + (((4 + quad) ^ (r & 7)) * 8)];
            for (int pi = 0; pi < 2; ++pi) {
                f32x4 z = {0.f, 0.f, 0.f, 0.f};
                z = __builtin_amdgcn_mfma_f32_16x16x32_bf16(aq[pi][0], b0, z, 0, 0, 0);
                z = __builtin_amdgcn_mfma_f32_16x16x32_bf16(aq[pi][1], b1, z, 0, 0, 0);
                s[pi][ni] = z;
            }
        }

        // online softmax (rows = pi*16 + quad*4 + r; cols spread over 16-lane group)
        for (int pi = 0; pi < 2; ++pi) {
            float mx[4];
            for (int r = 0; r < 4; ++r) {
                float m_ = s[pi][0][r];
                for (int ni = 1; ni < 8; ++ni) m_ = fmaxf(m_, s[pi][ni][r]);
                for (int off = 1; off < 16; off <<= 1) m_ = fmaxf(m_, __shfl_xor(m_, off, 16));
                mx[r] = m_;
            }
            for (int r = 0; r < 4; ++r) {
                float mn = fmaxf(mrow[pi][r], mx[r]);
                float alpha = __expf(mrow[pi][r] - mn);
                mrow[pi][r] = mn;
                lrow[pi][r] *= alpha;
                for (int nio = 0; nio < 4; ++nio) o[pi][nio][r] *= alpha;
            }
            float rs[4] = {0.f, 0.f, 0.f, 0.f};
            for (int ni = 0; ni < 8; ++ni) {
                f32x4 sv = s[pi][ni];
                for (int r = 0; r < 4; ++r) {
                    float p = __expf(sv[r] - mrow[pi][r]);
                    rs[r] += p;
                    int row = pi * 16 + quad * 4 + r;
                    int col = ni * 16 + lc;
                    int cg = col >> 3;
                    Pw[row * 128 + ((cg ^ (row & 15)) * 8) + (col & 7)] = f2bf(p);
                }
            }
            for (int r = 0; r < 4; ++r) {
                float v = rs[r];
                for (int off = 1; off < 16; off <<= 1) v += __shfl_xor(v, off, 16);
                lrow[pi][r] += v;
            }
        }

        // O += P V
        for (int kk = 0; kk < 4; ++kk) {
            int gq = kk * 4 + quad;
            short8 bv[4];
            for (int nio = 0; nio < 4; ++nio) {
                int n = nio * 16 + lc;
                bv[nio] = *(const short8*)&Vs[n * 128 + ((gq ^ (n & 15)) * 8)];
            }
            for (int pi = 0; pi < 2; ++pi) {
                int mr = pi * 16 + lc;
                short8 ap = *(const short8*)&Pw[mr * 128 + ((gq ^ (mr & 15)) * 8)];
                for (int nio = 0; nio < 4; ++nio)
                    o[pi][nio] = __builtin_amdgcn_mfma_f32_16x16x32_bf16(ap, bv[nio], o[pi][nio], 0, 0, 0);
            }
        }
        __syncthreads();
    }

    for (int pi = 0; pi < 2; ++pi) {
        float inv[4];
        for (int r = 0; r < 4; ++r) inv[r] = 1.f / lrow[pi][r];
        for (int nio = 0; nio < 4; ++nio)
            for (int r = 0; r < 4; ++r) {
                int row = qt * 128 + wave * 32 + pi * 16 + quad * 4 + r;
                int col = nio * 16 + lc;
                O[((size_t)bh * L_ + row) * DH_ + col] = f2bf(o[pi][nio][r] * inv[r]);
            }
    }
}

// -----------------------------------------------------------------------------
extern "C" void kernel_launch(void* const* d_in, const int* in_sizes, int n_in,
                              void* d_out, int out_size, void* d_ws, size_t ws_size,
                              hipStream_t stream) {
    (void)in_sizes; (void)n_in; (void)out_size; (void)ws_size;
    const float* x    = (const float*)d_in[0];
    const float* c    = (const float*)d_in[1];
    const float* Wq   = (const float*)d_in[2];
    const float* bq   = (const float*)d_in[3];
    const float* Wk   = (const float*)d_in[4];
    const float* bk   = (const float*)d_in[5];
    const float* Wv   = (const float*)d_in[6];
    const float* bv   = (const float*)d_in[7];
    const float* Wo   = (const float*)d_in[8];
    const float* bo   = (const float*)d_in[9];
    const float* W1   = (const float*)d_in[10];
    const float* b1   = (const float*)d_in[11];
    const float* W2   = (const float*)d_in[12];
    const float* b2   = (const float*)d_in[13];
    const float* Wada = (const float*)d_in[14];
    const float* bada = (const float*)d_in[15];

    char* w = (char*)d_ws;
    float*    ada  = (float*)(w + 0);                     // 49152 B
    ushort_t* Wqkv = (ushort_t*)(w + 49152);              // 6 MiB
    ushort_t* Wo_t = (ushort_t*)(w + 6340608);            // 2 MiB
    ushort_t* W1_t = (ushort_t*)(w + 8437760);            // 4 MiB
    ushort_t* W2_t = (ushort_t*)(w + 12632064);           // 4 MiB
    ushort_t* h    = (ushort_t*)(w + 16826368);           // 8 MiB (h, then h2)
    ushort_t* Qb   = (ushort_t*)(w + 25214976);           // 8 MiB
    ushort_t* Kb   = (ushort_t*)(w + 33603584);           // 8 MiB
    ushort_t* Vb   = (ushort_t*)(w + 41992192);           // 8 MiB
    ushort_t* Vtb  = (ushort_t*)(w + 50380800);           // 8 MiB
    float*    x1   = (float*)(w + 58769408);              // 16 MiB  (ends 75546624)
    ushort_t* Ob   = Vb;          // alias: Vb dead after transpose_v
    ushort_t* m1   = Qb;          // alias: Qb+Kb (16 MiB) dead after attn

    const int M = B_ * L_;  // 4096

    // weights -> bf16 B^T
    transpose_w<<<dim3(16, 16), 256, 0, stream>>>(Wq, Wqkv + 0,             D_, D_);
    transpose_w<<<dim3(16, 16), 256, 0, stream>>>(Wk, Wqkv + 1024 * 1024,   D_, D_);
    transpose_w<<<dim3(16, 16), 256, 0, stream>>>(Wv, Wqkv + 2 * 1024 * 1024, D_, D_);
    transpose_w<<<dim3(16, 16), 256, 0, stream>>>(Wo, Wo_t, D_, D_);
    transpose_w<<<dim3(32, 16), 256, 0, stream>>>(W1, W1_t, D_, FF_);
    transpose_w<<<dim3(16, 32), 256, 0, stream>>>(W2, W2_t, FF_, D_);

    ada_gemv<<<dim3(24, 2), 256, 0, stream>>>(c, Wada, bada, ada);
    ln_mod<<<M, 256, 0, stream>>>(x, ada, 0, 1024, h);

    EpiArgs e0 = {bq, bk, bv, Qb, Kb, Vb, nullptr, nullptr, nullptr};
    gemm_bt<0><<<dim3(32, 24), 256, 0, stream>>>(h, Wqkv, M, 3072, D_, e0);

    transpose_v<<<dim3(32, 32), 256, 0, stream>>>(Vb, Vtb);
    attn<<<dim3(16, 32), 256, 0, stream>>>(Qb, Kb, Vtb, Ob);

    EpiArgs e1 = {bo, nullptr, nullptr, nullptr, nullptr, nullptr, x, ada + 2048, x1};
    gemm_bt<2><<<dim3(32, 8), 256, 0, stream>>>(Ob, Wo_t, M, D_, D_, e1);

    ln_mod<<<M, 256, 0, stream>>>(x1, ada, 3072, 4096, h);

    EpiArgs e2 = {b1, nullptr, nullptr, m1, nullptr, nullptr, nullptr, nullptr, nullptr};
    gemm_bt<1><<<dim3(32, 16), 256, 0, stream>>>(h, W1_t, M, FF_, D_, e2);

    EpiArgs e3 = {b2, nullptr, nullptr, nullptr, nullptr, nullptr, x1, ada + 5120, (float*)d_out};
    gemm_bt<2><<<dim3(32, 8), 256, 0, stream>>>(m1, W2_t, M, D_, FF_, e3);
}

// Round 4
// 489.144 us; speedup vs baseline: 1.2900x; 1.2900x over previous
//
#include <hip/hip_runtime.h>
#include <hip/hip_bf16.h>

typedef unsigned short ushort_t;
typedef __bf16 bf16x8 __attribute__((ext_vector_type(8)));
typedef float f32x4 __attribute__((ext_vector_type(4)));

typedef unsigned int u32;
typedef u32 __attribute__((address_space(1))) global_u32;
typedef u32 __attribute__((address_space(3))) lds_u32;

#define D_ 1024
#define L_ 2048
#define B_ 2
#define H_ 16
#define DH_ 64
#define FF_ 2048
#define ADA_ 6144

#define MFMA __builtin_amdgcn_mfma_f32_16x16x32_bf16

__device__ __forceinline__ ushort_t f2bf(float f) {
    union { float f; u32 u; } v; v.f = f;
    u32 r = v.u + 0x7fffu + ((v.u >> 16) & 1u);
    return (ushort_t)(r >> 16);
}

__device__ __forceinline__ void llds16(const ushort_t* src, ushort_t* dst) {
    __builtin_amdgcn_global_load_lds((global_u32*)src, (lds_u32*)dst, 16, 0, 0);
}

// ---------------- weight transpose+convert: W (K,N) fp32 -> Wt (N,K) bf16 ----
__global__ void transpose_w(const float* __restrict__ W, ushort_t* __restrict__ Wt,
                            int K, int N) {
    __shared__ float tile[64][65];
    int n0 = blockIdx.x * 64, k0 = blockIdx.y * 64;
    int t = threadIdx.x;
    for (int p = 0; p < 4; ++p) {
        int k = p * 16 + (t >> 4), nn = (t & 15) * 4;
        float4 v = *(const float4*)(W + (size_t)(k0 + k) * N + n0 + nn);
        tile[k][nn] = v.x; tile[k][nn + 1] = v.y; tile[k][nn + 2] = v.z; tile[k][nn + 3] = v.w;
    }
    __syncthreads();
    for (int p = 0; p < 4; ++p) {
        int n = p * 16 + (t >> 4), kk = (t & 15) * 4;
        ushort4 o;
        o.x = f2bf(tile[kk][n]); o.y = f2bf(tile[kk + 1][n]);
        o.z = f2bf(tile[kk + 2][n]); o.w = f2bf(tile[kk + 3][n]);
        *(ushort4*)(Wt + (size_t)(n0 + n) * K + k0 + kk) = o;
    }
}

// ---------------- V transpose: (BH, L, DH) bf16 -> (BH, DH, L) bf16 ----------
__global__ void transpose_v(const ushort_t* __restrict__ V, ushort_t* __restrict__ Vt) {
    __shared__ ushort_t tile[64][72];
    int bh = blockIdx.y, l0 = blockIdx.x * 64;
    const ushort_t* Vb = V + ((size_t)bh * L_ + l0) * DH_;
    ushort_t* Vtb = Vt + (size_t)bh * DH_ * L_;
    int t = threadIdx.x;
    for (int p = 0; p < 2; ++p) {
        int i = p * 32 + (t >> 3), d0 = (t & 7) * 8;
        ushort4 v0 = *(const ushort4*)(Vb + (size_t)i * DH_ + d0);
        ushort4 v1 = *(const ushort4*)(Vb + (size_t)i * DH_ + d0 + 4);
        tile[d0 + 0][i] = v0.x; tile[d0 + 1][i] = v0.y; tile[d0 + 2][i] = v0.z; tile[d0 + 3][i] = v0.w;
        tile[d0 + 4][i] = v1.x; tile[d0 + 5][i] = v1.y; tile[d0 + 6][i] = v1.z; tile[d0 + 7][i] = v1.w;
    }
    __syncthreads();
    for (int p = 0; p < 2; ++p) {
        int dh = p * 32 + (t >> 3), j0 = (t & 7) * 8;
        ushort4 o0, o1;
        o0.x = tile[dh][j0 + 0]; o0.y = tile[dh][j0 + 1]; o0.z = tile[dh][j0 + 2]; o0.w = tile[dh][j0 + 3];
        o1.x = tile[dh][j0 + 4]; o1.y = tile[dh][j0 + 5]; o1.z = tile[dh][j0 + 6]; o1.w = tile[dh][j0 + 7];
        *(ushort4*)(Vtb + (size_t)dh * L_ + l0 + j0) = o0;
        *(ushort4*)(Vtb + (size_t)dh * L_ + l0 + j0 + 4) = o1;
    }
}

// ---------------- ada = silu(c) @ Wada + bada  (fp32 GEMV, B=2) --------------
__global__ void ada_gemv(const float* __restrict__ c, const float* __restrict__ Wada,
                         const float* __restrict__ bada, float* __restrict__ ada) {
    int b = blockIdx.y;
    int j = blockIdx.x * 256 + threadIdx.x;
    __shared__ float s[D_];
    for (int d = threadIdx.x; d < D_; d += 256) {
        float v = c[(size_t)b * D_ + d];
        s[d] = v / (1.f + __expf(-v));
    }
    __syncthreads();
    float acc = 0.f;
#pragma unroll 8
    for (int d = 0; d < D_; ++d)
        acc = fmaf(s[d], Wada[(size_t)d * ADA_ + j], acc);
    ada[(size_t)b * ADA_ + j] = acc + bada[j];
}

// ---------------- LayerNorm + modulation -> bf16 -----------------------------
__global__ void ln_mod(const float* __restrict__ x, const float* __restrict__ ada,
                       int so, int co, ushort_t* __restrict__ out) {
    int row = blockIdx.x;
    int b = row >> 11;
    float4 v = ((const float4*)(x + (size_t)row * D_))[threadIdx.x];
    float sum = v.x + v.y + v.z + v.w;
    float sq = v.x * v.x + v.y * v.y + v.z * v.z + v.w * v.w;
    for (int off = 32; off; off >>= 1) { sum += __shfl_down(sum, off); sq += __shfl_down(sq, off); }
    __shared__ float sa[4], sb[4];
    int wave = threadIdx.x >> 6, lane = threadIdx.x & 63;
    if (lane == 0) { sa[wave] = sum; sb[wave] = sq; }
    __syncthreads();
    sum = sa[0] + sa[1] + sa[2] + sa[3];
    sq = sb[0] + sb[1] + sb[2] + sb[3];
    float mean = sum * (1.f / 1024.f);
    float var = sq * (1.f / 1024.f) - mean * mean;
    float rstd = rsqrtf(var + 1e-6f);
    int d = threadIdx.x * 4;
    const float* shf = ada + (size_t)b * ADA_ + so;
    const float* scf = ada + (size_t)b * ADA_ + co;
    ushort4 ov;
    ov.x = f2bf((v.x - mean) * rstd * (1.f + scf[d + 0]) + shf[d + 0]);
    ov.y = f2bf((v.y - mean) * rstd * (1.f + scf[d + 1]) + shf[d + 1]);
    ov.z = f2bf((v.z - mean) * rstd * (1.f + scf[d + 2]) + shf[d + 2]);
    ov.w = f2bf((v.w - mean) * rstd * (1.f + scf[d + 3]) + shf[d + 3]);
    *(ushort4*)(out + (size_t)row * D_ + d) = ov;
}

// ---------------- GEMM: A (M,K) bf16 row-major, Bt (N,K) bf16 row-major ------
struct EpiArgs {
    const float* bias0; const float* bias1; const float* bias2;
    ushort_t* o0; ushort_t* o1; ushort_t* o2;
    const float* resid; const float* gate;
    float* fout;
};

template <int EPI>
__device__ __forceinline__ void epi_store(float v, int m, int n, int N, const EpiArgs& e) {
    if (EPI == 0) {  // QKV -> (B,H,L,DH) bf16, Q pre-scaled by 1/8
        int which = n >> 10, cc = n & 1023;
        const float* bias = which == 0 ? e.bias0 : which == 1 ? e.bias1 : e.bias2;
        ushort_t* ob = which == 0 ? e.o0 : which == 1 ? e.o1 : e.o2;
        v += bias[cc];
        if (which == 0) v *= 0.125f;
        int b = m >> 11, l = m & 2047, h = cc >> 6, dh = cc & 63;
        ob[(((size_t)(b * H_ + h) * L_) + l) * DH_ + dh] = f2bf(v);
    } else if (EPI == 1) {  // bias + exact GELU -> bf16
        v += e.bias0[n];
        v = 0.5f * v * (1.f + erff(v * 0.70710678118f));
        e.o0[(size_t)m * N + n] = f2bf(v);
    } else {  // residual + gate -> fp32
        int b = m >> 11;
        e.fout[(size_t)m * N + n] =
            e.resid[(size_t)m * N + n] + e.gate[(size_t)b * ADA_ + n] * (v + e.bias0[n]);
    }
}

template <int EPI>
__device__ __forceinline__ void st4(const f32x4& cc, int mb, int n, int N, const EpiArgs& e) {
#pragma unroll
    for (int r = 0; r < 4; ++r) epi_store<EPI>(cc[r], mb + r, n, N, e);
}

template <int EPI>
__global__ __launch_bounds__(256, 2) void gemm_bt(
    const ushort_t* __restrict__ A, const ushort_t* __restrict__ Bt,
    int M, int N, int K, EpiArgs e) {
    __shared__ ushort_t As[128 * 64];
    __shared__ ushort_t Bs[128 * 64];
    int m0 = blockIdx.x * 128, n0 = blockIdx.y * 128;
    int tid = threadIdx.x, wave = tid >> 6, lane = tid & 63;
    int quad = lane >> 4, lc = lane & 15;
    int wm = (wave & 1) * 64, wn = (wave >> 1) * 64;
    int srow = lane >> 3, sg = lane & 7;
    int sw = lc & 7;  // fragment-row swizzle group: (wm+mi*16+lc)&7 == lc&7

    f32x4 c00 = {}, c01 = {}, c02 = {}, c03 = {};
    f32x4 c10 = {}, c11 = {}, c12 = {}, c13 = {};
    f32x4 c20 = {}, c21 = {}, c22 = {}, c23 = {};
    f32x4 c30 = {}, c31 = {}, c32 = {}, c33 = {};

    for (int k0 = 0; k0 < K; k0 += 64) {
#pragma unroll
        for (int i = 0; i < 8; ++i) {
            int chunk = wave * 8 + i;
            int c = chunk & 15;
            int row = c * 8 + srow;
            int g = sg ^ (row & 7);
            if (chunk < 16)
                llds16(A + (size_t)(m0 + row) * K + k0 + g * 8, &As[c * 512 + lane * 8]);
            else
                llds16(Bt + (size_t)(n0 + row) * K + k0 + g * 8, &Bs[c * 512 + lane * 8]);
        }
        __syncthreads();
#pragma unroll
        for (int kk = 0; kk < 2; ++kk) {
            int off = ((kk * 4 + quad) ^ sw) * 8;
            bf16x8 a0 = *(const bf16x8*)&As[(wm +  0 + lc) * 64 + off];
            bf16x8 a1 = *(const bf16x8*)&As[(wm + 16 + lc) * 64 + off];
            bf16x8 a2 = *(const bf16x8*)&As[(wm + 32 + lc) * 64 + off];
            bf16x8 a3 = *(const bf16x8*)&As[(wm + 48 + lc) * 64 + off];
            bf16x8 b0 = *(const bf16x8*)&Bs[(wn +  0 + lc) * 64 + off];
            bf16x8 b1 = *(const bf16x8*)&Bs[(wn + 16 + lc) * 64 + off];
            bf16x8 b2 = *(const bf16x8*)&Bs[(wn + 32 + lc) * 64 + off];
            bf16x8 b3 = *(const bf16x8*)&Bs[(wn + 48 + lc) * 64 + off];
            c00 = MFMA(a0, b0, c00, 0, 0, 0); c01 = MFMA(a0, b1, c01, 0, 0, 0);
            c02 = MFMA(a0, b2, c02, 0, 0, 0); c03 = MFMA(a0, b3, c03, 0, 0, 0);
            c10 = MFMA(a1, b0, c10, 0, 0, 0); c11 = MFMA(a1, b1, c11, 0, 0, 0);
            c12 = MFMA(a1, b2, c12, 0, 0, 0); c13 = MFMA(a1, b3, c13, 0, 0, 0);
            c20 = MFMA(a2, b0, c20, 0, 0, 0); c21 = MFMA(a2, b1, c21, 0, 0, 0);
            c22 = MFMA(a2, b2, c22, 0, 0, 0); c23 = MFMA(a2, b3, c23, 0, 0, 0);
            c30 = MFMA(a3, b0, c30, 0, 0, 0); c31 = MFMA(a3, b1, c31, 0, 0, 0);
            c32 = MFMA(a3, b2, c32, 0, 0, 0); c33 = MFMA(a3, b3, c33, 0, 0, 0);
        }
        __syncthreads();
    }

    int mb = m0 + wm + quad * 4, nb = n0 + wn + lc;
    st4<EPI>(c00, mb +  0, nb +  0, N, e); st4<EPI>(c01, mb +  0, nb + 16, N, e);
    st4<EPI>(c02, mb +  0, nb + 32, N, e); st4<EPI>(c03, mb +  0, nb + 48, N, e);
    st4<EPI>(c10, mb + 16, nb +  0, N, e); st4<EPI>(c11, mb + 16, nb + 16, N, e);
    st4<EPI>(c12, mb + 16, nb + 32, N, e); st4<EPI>(c13, mb + 16, nb + 48, N, e);
    st4<EPI>(c20, mb + 32, nb +  0, N, e); st4<EPI>(c21, mb + 32, nb + 16, N, e);
    st4<EPI>(c22, mb + 32, nb + 32, N, e); st4<EPI>(c23, mb + 32, nb + 48, N, e);
    st4<EPI>(c30, mb + 48, nb +  0, N, e); st4<EPI>(c31, mb + 48, nb + 16, N, e);
    st4<EPI>(c32, mb + 48, nb + 32, N, e); st4<EPI>(c33, mb + 48, nb + 48, N, e);
}

// ---------------- flash attention: Q pre-scaled, per (b,h,qtile) -------------
__global__ __launch_bounds__(256, 2) void attn(
    const ushort_t* __restrict__ Q, const ushort_t* __restrict__ Kx,
    const ushort_t* __restrict__ Vt, ushort_t* __restrict__ O) {
    __shared__ ushort_t Qs[128 * 64], Ks[128 * 64], Vs[64 * 128], Ps[4 * 32 * 128];
    int qt = blockIdx.x, bh = blockIdx.y;
    const ushort_t* Qg = Q + ((size_t)bh * L_ + qt * 128) * DH_;
    const ushort_t* Kg = Kx + (size_t)bh * L_ * DH_;
    const ushort_t* Vg = Vt + (size_t)bh * DH_ * L_;
    int tid = threadIdx.x, wave = tid >> 6, lane = tid & 63;
    int quad = lane >> 4, lc = lane & 15;

    {   // stage Q (wave w stages exactly the rows it will consume)
        int srow = lane >> 3, sg = lane & 7;
#pragma unroll
        for (int i = 0; i < 4; ++i) {
            int c = wave * 4 + i;
            int row = c * 8 + srow;
            int g = sg ^ (row & 7);
            llds16(Qg + (size_t)row * DH_ + g * 8, &Qs[c * 512 + lane * 8]);
        }
    }

    f32x4 o00 = {}, o01 = {}, o02 = {}, o03 = {};
    f32x4 o10 = {}, o11 = {}, o12 = {}, o13 = {};
    float mrow[2][4], lrow[2][4];
#pragma unroll
    for (int pi = 0; pi < 2; ++pi)
#pragma unroll
        for (int r = 0; r < 4; ++r) { mrow[pi][r] = -1e30f; lrow[pi][r] = 0.f; }
    ushort_t* Pw = &Ps[wave * 4096];
    int sw = lc & 7;

    for (int t = 0; t < 16; ++t) {
        {   // stage K tile (chunks 0..15) and Vt tile (chunks 16..31)
            int srow = lane >> 3, sg = lane & 7;
#pragma unroll
            for (int i = 0; i < 8; ++i) {
                int chunk = wave * 8 + i;
                if (chunk < 16) {
                    int row = chunk * 8 + srow;
                    int g = sg ^ (row & 7);
                    llds16(Kg + ((size_t)(t * 128 + row)) * DH_ + g * 8, &Ks[chunk * 512 + lane * 8]);
                } else {
                    int c2 = chunk - 16;
                    int row = c2 * 4 + (lane >> 4);
                    int g = (lane & 15) ^ (row & 15);
                    llds16(Vg + (size_t)row * L_ + t * 128 + g * 8, &Vs[c2 * 512 + lane * 8]);
                }
            }
        }
        __syncthreads();

        // S = Q K^T for this wave's 32 q-rows
        f32x4 s[2][8];
#pragma unroll
        for (int kk = 0; kk < 2; ++kk) {
            int off = ((kk * 4 + quad) ^ sw) * 8;
            bf16x8 aq0 = *(const bf16x8*)&Qs[(wave * 32 +  0 + lc) * 64 + off];
            bf16x8 aq1 = *(const bf16x8*)&Qs[(wave * 32 + 16 + lc) * 64 + off];
#pragma unroll
            for (int ni = 0; ni < 8; ++ni) {
                bf16x8 bk = *(const bf16x8*)&Ks[(ni * 16 + lc) * 64 + off];
                if (kk == 0) {
                    f32x4 z = {0.f, 0.f, 0.f, 0.f};
                    s[0][ni] = MFMA(aq0, bk, z, 0, 0, 0);
                    s[1][ni] = MFMA(aq1, bk, z, 0, 0, 0);
                } else {
                    s[0][ni] = MFMA(aq0, bk, s[0][ni], 0, 0, 0);
                    s[1][ni] = MFMA(aq1, bk, s[1][ni], 0, 0, 0);
                }
            }
        }

        // online softmax (rows = pi*16 + quad*4 + r; cols spread over 16-lane group)
#pragma unroll
        for (int pi = 0; pi < 2; ++pi) {
            float mx[4];
#pragma unroll
            for (int r = 0; r < 4; ++r) {
                float m_ = s[pi][0][r];
#pragma unroll
                for (int ni = 1; ni < 8; ++ni) m_ = fmaxf(m_, s[pi][ni][r]);
#pragma unroll
                for (int off = 1; off < 16; off <<= 1) m_ = fmaxf(m_, __shfl_xor(m_, off, 16));
                mx[r] = m_;
            }
#pragma unroll
            for (int r = 0; r < 4; ++r) {
                float mn = fmaxf(mrow[pi][r], mx[r]);
                float alpha = __expf(mrow[pi][r] - mn);
                mrow[pi][r] = mn;
                lrow[pi][r] *= alpha;
                if (pi == 0) { o00[r] *= alpha; o01[r] *= alpha; o02[r] *= alpha; o03[r] *= alpha; }
                else         { o10[r] *= alpha; o11[r] *= alpha; o12[r] *= alpha; o13[r] *= alpha; }
            }
            float rs0 = 0.f, rs1 = 0.f, rs2 = 0.f, rs3 = 0.f;
#pragma unroll
            for (int ni = 0; ni < 8; ++ni) {
                f32x4 sv = s[pi][ni];
#pragma unroll
                for (int r = 0; r < 4; ++r) {
                    float p = __expf(sv[r] - mrow[pi][r]);
                    if (r == 0) rs0 += p; else if (r == 1) rs1 += p; else if (r == 2) rs2 += p; else rs3 += p;
                    int row = pi * 16 + quad * 4 + r;
                    int col = ni * 16 + lc;
                    int cg = col >> 3;
                    Pw[row * 128 + ((cg ^ (row & 15)) * 8) + (col & 7)] = f2bf(p);
                }
            }
            float rsx[4] = {rs0, rs1, rs2, rs3};
#pragma unroll
            for (int r = 0; r < 4; ++r) {
                float v = rsx[r];
#pragma unroll
                for (int off = 1; off < 16; off <<= 1) v += __shfl_xor(v, off, 16);
                lrow[pi][r] += v;
            }
        }

        // O += P V   (P rows: mr&15 swizzle; V rows: n&15 swizzle)
#pragma unroll
        for (int kk = 0; kk < 4; ++kk) {
            int gq = kk * 4 + quad;
            bf16x8 bv0 = *(const bf16x8*)&Vs[( 0 + lc) * 128 + ((gq ^ (( 0 + lc) & 15)) * 8)];
            bf16x8 bv1 = *(const bf16x8*)&Vs[(16 + lc) * 128 + ((gq ^ ((16 + lc) & 15)) * 8)];
            bf16x8 bv2 = *(const bf16x8*)&Vs[(32 + lc) * 128 + ((gq ^ ((32 + lc) & 15)) * 8)];
            bf16x8 bv3 = *(const bf16x8*)&Vs[(48 + lc) * 128 + ((gq ^ ((48 + lc) & 15)) * 8)];
            bf16x8 ap0 = *(const bf16x8*)&Pw[( 0 + lc) * 128 + ((gq ^ (( 0 + lc) & 15)) * 8)];
            bf16x8 ap1 = *(const bf16x8*)&Pw[(16 + lc) * 128 + ((gq ^ ((16 + lc) & 15)) * 8)];
            o00 = MFMA(ap0, bv0, o00, 0, 0, 0); o01 = MFMA(ap0, bv1, o01, 0, 0, 0);
            o02 = MFMA(ap0, bv2, o02, 0, 0, 0); o03 = MFMA(ap0, bv3, o03, 0, 0, 0);
            o10 = MFMA(ap1, bv0, o10, 0, 0, 0); o11 = MFMA(ap1, bv1, o11, 0, 0, 0);
            o12 = MFMA(ap1, bv2, o12, 0, 0, 0); o13 = MFMA(ap1, bv3, o13, 0, 0, 0);
        }
        __syncthreads();
    }

#pragma unroll
    for (int pi = 0; pi < 2; ++pi) {
#pragma unroll
        for (int nio = 0; nio < 4; ++nio) {
            const f32x4& ov = pi == 0 ? (nio == 0 ? o00 : nio == 1 ? o01 : nio == 2 ? o02 : o03)
                                      : (nio == 0 ? o10 : nio == 1 ? o11 : nio == 2 ? o12 : o13);
#pragma unroll
            for (int r = 0; r < 4; ++r) {
                int row = qt * 128 + wave * 32 + pi * 16 + quad * 4 + r;
                int col = nio * 16 + lc;
                O[((size_t)bh * L_ + row) * DH_ + col] = f2bf(ov[r] / lrow[pi][r]);
            }
        }
    }
}

// -----------------------------------------------------------------------------
extern "C" void kernel_launch(void* const* d_in, const int* in_sizes, int n_in,
                              void* d_out, int out_size, void* d_ws, size_t ws_size,
                              hipStream_t stream) {
    (void)in_sizes; (void)n_in; (void)out_size; (void)ws_size;
    const float* x    = (const float*)d_in[0];
    const float* c    = (const float*)d_in[1];
    const float* Wq   = (const float*)d_in[2];
    const float* bq   = (const float*)d_in[3];
    const float* Wk   = (const float*)d_in[4];
    const float* bk   = (const float*)d_in[5];
    const float* Wv   = (const float*)d_in[6];
    const float* bv   = (const float*)d_in[7];
    const float* Wo   = (const float*)d_in[8];
    const float* bo   = (const float*)d_in[9];
    const float* W1   = (const float*)d_in[10];
    const float* b1   = (const float*)d_in[11];
    const float* W2   = (const float*)d_in[12];
    const float* b2   = (const float*)d_in[13];
    const float* Wada = (const float*)d_in[14];
    const float* bada = (const float*)d_in[15];

    char* w = (char*)d_ws;
    float*    ada  = (float*)(w + 0);                     // 49152 B
    ushort_t* Wqkv = (ushort_t*)(w + 49152);              // 6 MiB
    ushort_t* Wo_t = (ushort_t*)(w + 6340608);            // 2 MiB
    ushort_t* W1_t = (ushort_t*)(w + 8437760);            // 4 MiB
    ushort_t* W2_t = (ushort_t*)(w + 12632064);           // 4 MiB
    ushort_t* h    = (ushort_t*)(w + 16826368);           // 8 MiB (h, then h2)
    ushort_t* Qb   = (ushort_t*)(w + 25214976);           // 8 MiB
    ushort_t* Kb   = (ushort_t*)(w + 33603584);           // 8 MiB
    ushort_t* Vb   = (ushort_t*)(w + 41992192);           // 8 MiB
    ushort_t* Vtb  = (ushort_t*)(w + 50380800);           // 8 MiB
    float*    x1   = (float*)(w + 58769408);              // 16 MiB  (ends 75546624)
    ushort_t* Ob   = Vb;          // alias: Vb dead after transpose_v
    ushort_t* m1   = Qb;          // alias: Qb+Kb (16 MiB) dead after attn

    const int M = B_ * L_;  // 4096

    // weights -> bf16 B^T
    transpose_w<<<dim3(16, 16), 256, 0, stream>>>(Wq, Wqkv + 0,             D_, D_);
    transpose_w<<<dim3(16, 16), 256, 0, stream>>>(Wk, Wqkv + 1024 * 1024,   D_, D_);
    transpose_w<<<dim3(16, 16), 256, 0, stream>>>(Wv, Wqkv + 2 * 1024 * 1024, D_, D_);
    transpose_w<<<dim3(16, 16), 256, 0, stream>>>(Wo, Wo_t, D_, D_);
    transpose_w<<<dim3(32, 16), 256, 0, stream>>>(W1, W1_t, D_, FF_);
    transpose_w<<<dim3(16, 32), 256, 0, stream>>>(W2, W2_t, FF_, D_);

    ada_gemv<<<dim3(24, 2), 256, 0, stream>>>(c, Wada, bada, ada);
    ln_mod<<<M, 256, 0, stream>>>(x, ada, 0, 1024, h);

    EpiArgs e0 = {bq, bk, bv, Qb, Kb, Vb, nullptr, nullptr, nullptr};
    gemm_bt<0><<<dim3(32, 24), 256, 0, stream>>>(h, Wqkv, M, 3072, D_, e0);

    transpose_v<<<dim3(32, 32), 256, 0, stream>>>(Vb, Vtb);
    attn<<<dim3(16, 32), 256, 0, stream>>>(Qb, Kb, Vtb, Ob);

    EpiArgs e1 = {bo, nullptr, nullptr, nullptr, nullptr, nullptr, x, ada + 2048, x1};
    gemm_bt<2><<<dim3(32, 8), 256, 0, stream>>>(Ob, Wo_t, M, D_, D_, e1);

    ln_mod<<<M, 256, 0, stream>>>(x1, ada, 3072, 4096, h);

    EpiArgs e2 = {b1, nullptr, nullptr, m1, nullptr, nullptr, nullptr, nullptr, nullptr};
    gemm_bt<1><<<dim3(32, 16), 256, 0, stream>>>(h, W1_t, M, FF_, D_, e2);

    EpiArgs e3 = {b2, nullptr, nullptr, nullptr, nullptr, nullptr, x1, ada + 5120, (float*)d_out};
    gemm_bt<2><<<dim3(32, 8), 256, 0, stream>>>(m1, W2_t, M, D_, FF_, e3);
}